// Round 11
// baseline (157.093 us; speedup 1.0000x reference)
//
#include <hip/hip_runtime.h>
#include <math.h>

// Problem constants (B, S, E, WIN) = (8, 2048, 512, 11)
#define B_    8
#define S_    2048
#define E_    512
#define WIN_  11
#define WW    5              // WIN/2
#define F4C   1408           // float4 per W row (5632/4)
#define E4C   128            // float4 per x row (512/4)
#define PSTR  (B_ * WIN_)    // 88 gate logits per s

// ---- DPP wave-sum: 6 VALU ops, zero DS-pipe traffic. Full sum -> lane 63.
template <int CTRL, int RMASK>
__device__ __forceinline__ float dpp_add(float v) {
    int sh = __builtin_amdgcn_update_dpp(0, __float_as_int(v),
                                         CTRL, RMASK, 0xF, true);
    return v + __int_as_float(sh);
}
__device__ __forceinline__ float wave_sum63(float v) {
    v = dpp_add<0x111, 0xF>(v);   // row_shr:1
    v = dpp_add<0x112, 0xF>(v);   // row_shr:2
    v = dpp_add<0x114, 0xF>(v);   // row_shr:4
    v = dpp_add<0x118, 0xF>(v);   // row_shr:8
    v = dpp_add<0x142, 0xA>(v);   // row_bcast:15
    v = dpp_add<0x143, 0xC>(v);   // row_bcast:31 -> lane 63 = full sum
    return v;
}

__device__ __forceinline__ float tanh_fast(float v) {
    const float e = __expf(v + v);
    return 1.f - 2.f / (e + 1.f);
}

// ---------------------------------------------------------------------------
// Fused, x-dedup (R10) + TRUE double-buffer with counted vmcnt (T4):
//   prologue: STAGE(buf0, wpLo)
//   iter wp : STAGE(buf[cur^1], wp+1)         <- issued BEFORE compute
//             s_waitcnt vmcnt(K_next)          <- waits ONLY for buf[cur]'s
//                loads (the K_next just-issued stay in flight across compute;
//                R8's failure was __syncthreads() draining vmcnt(0) here)
//             s_barrier; sched_barrier(0)      <- rule #18 hoist fence
//             compute chunk wp from buf[cur]
//             s_barrier                        <- WAR before overwriting
// Per chunk both W (22.5 KB, HBM-unique) and x row (16 KB, L2/L3) are staged
// via global_load_lds(16B). Waves 0-1 issue 10 loads/chunk, waves 2-3 issue 9
// (wave-uniform), so the counted waitcnt is branch-selected per wave.
// LDS 76.3 KB -> 2 blocks/CU; Little's law: 2 x 38.5 KB in flight covers the
// 10.25 B/cyc/CU HBM share with ~8x margin.
// ---------------------------------------------------------------------------
__global__ __launch_bounds__(256)
void win_attn_fused(const float* __restrict__ x,
                    const float* __restrict__ W,
                    const float* __restrict__ bias,
                    float* __restrict__ out)
{
    const int bid  = blockIdx.x;
    const int s    = (bid & 7) * (S_ / 8) + (bid >> 3);   // bijective XCD swizzle
    const int tid  = threadIdx.x;
    const int wid  = tid >> 6;      // wave 0..3
    const int lane = tid & 63;

    const float4* __restrict__ X4 = reinterpret_cast<const float4*>(x);
    const float4* __restrict__ Ws = reinterpret_cast<const float4*>(W)
                                    + (size_t)s * (WIN_ * F4C);

    __shared__ float4 Wbuf[2][WIN_ * E4C];   // 2 x 22.5 KB
    __shared__ float4 xbuf[2][B_ * E4C];     // 2 x 16 KB
    __shared__ float gates[PSTR];

    const int w0   = wid * 3;                  // first w-row of this wave
    const int wcnt = (wid == 3) ? 2 : 3;       // wave 3 owns rows 9,10

    // stage chunk wp into buffer `buf`: 1408 W f4 + 1024 x f4 = 2432 f4.
    // j=0..4: W; j=5: W for waves 0-1, x for waves 2-3... (see mapping below)
    // all branches are wave-uniform; waves 0-1 issue 10 gl_lds, waves 2-3: 9.
    auto STAGE = [&](int buf, int wp) {
        const int row = s - WW + wp;
        #pragma unroll
        for (int j = 0; j < 10; ++j) {
            const int m = j * 256 + tid;       // [0, 2560)
            if (j < 9 || tid < 128) {          // m < 2432 (wave-uniform)
                if (m < 1408) {                // W piece (wave-uniform per j)
                    const int w  = m >> 7;
                    const int e4 = m & 127;
                    const float4* src = Ws + (size_t)w * F4C + wp * E4C + e4;
                    __builtin_amdgcn_global_load_lds(
                        (const __attribute__((address_space(1))) void*)src,
                        (__attribute__((address_space(3))) void*)&Wbuf[buf][m],
                        16, 0, 0);
                } else {                       // x piece
                    const int n  = m - 1408;
                    const int b  = n >> 7;
                    const int e4 = n & 127;
                    const float4* src = X4 + ((size_t)b * S_ + row) * E4C + e4;
                    __builtin_amdgcn_global_load_lds(
                        (const __attribute__((address_space(1))) void*)src,
                        (__attribute__((address_space(3))) void*)&xbuf[buf][n],
                        16, 0, 0);
                }
            }
        }
    };

    float acc[B_][3];
    #pragma unroll
    for (int b = 0; b < B_; ++b)
        #pragma unroll
        for (int j = 0; j < 3; ++j) acc[b][j] = 0.f;

    const int wpLo = (s >= WW) ? 0 : (WW - s);
    const int wpHi = (WIN_ < S_ + WW - s) ? WIN_ : (S_ + WW - s);

    STAGE(0, wpLo);
    int cur = 0;

    #pragma unroll 1
    for (int wp = wpLo; wp < wpHi; ++wp) {
        const bool more = (wp + 1 < wpHi);
        if (more) STAGE(cur ^ 1, wp + 1);   // next chunk's loads fly over compute

        // wait for buf[cur]'s loads only (retire in order -> all-but-newest-K)
        if (more) {
            if (wid < 2) asm volatile("s_waitcnt vmcnt(10)" ::: "memory");
            else         asm volatile("s_waitcnt vmcnt(9)"  ::: "memory");
        } else {
            asm volatile("s_waitcnt vmcnt(0)" ::: "memory");
        }
        __builtin_amdgcn_s_barrier();
        __builtin_amdgcn_sched_barrier(0);   // pin: no ds_read hoist above wait

        // ---- compute chunk wp from buf[cur] ----
        float4 wv[3][2];
        #pragma unroll
        for (int j = 0; j < 3; ++j)
            if (j < wcnt) {
                wv[j][0] = Wbuf[cur][(w0 + j) * E4C + lane];
                wv[j][1] = Wbuf[cur][(w0 + j) * E4C + lane + 64];
            }

        #pragma unroll
        for (int half = 0; half < 2; ++half) {
            float4 xv[4][2];
            #pragma unroll
            for (int bb = 0; bb < 4; ++bb) {
                const int b = half * 4 + bb;
                xv[bb][0] = xbuf[cur][b * E4C + lane];
                xv[bb][1] = xbuf[cur][b * E4C + lane + 64];
            }
            #pragma unroll
            for (int bb = 0; bb < 4; ++bb) {
                const int b = half * 4 + bb;
                #pragma unroll
                for (int j = 0; j < 3; ++j)
                    if (j < wcnt) {
                        float a = acc[b][j];
                        a = fmaf(xv[bb][0].x, wv[j][0].x, a);
                        a = fmaf(xv[bb][0].y, wv[j][0].y, a);
                        a = fmaf(xv[bb][0].z, wv[j][0].z, a);
                        a = fmaf(xv[bb][0].w, wv[j][0].w, a);
                        a = fmaf(xv[bb][1].x, wv[j][1].x, a);
                        a = fmaf(xv[bb][1].y, wv[j][1].y, a);
                        a = fmaf(xv[bb][1].z, wv[j][1].z, a);
                        a = fmaf(xv[bb][1].w, wv[j][1].w, a);
                        acc[b][j] = a;
                    }
            }
        }
        __builtin_amdgcn_sched_barrier(0);
        __builtin_amdgcn_s_barrier();   // WAR: all reads done before buf[cur]
        cur ^= 1;                       // is overwritten next iteration
    }

    // ---- DPP reduce (VALU only) -> gate logits -> sigmoid ----
    #pragma unroll
    for (int b = 0; b < B_; ++b)
        #pragma unroll
        for (int j = 0; j < 3; ++j)
            if (j < wcnt) acc[b][j] = wave_sum63(acc[b][j]);

    if (lane == 63) {
        #pragma unroll
        for (int b = 0; b < B_; ++b)
            #pragma unroll
            for (int j = 0; j < 3; ++j)
                if (j < wcnt) gates[b * WIN_ + w0 + j] = acc[b][j];
    }
    __syncthreads();

    if (tid < PSTR) {
        const int w = tid % WIN_;
        const float v = gates[tid] + bias[s * WIN_ + w];
        gates[tid] = 1.f / (1.f + __expf(-v));
    }
    __syncthreads();

    // ---- score + tanh (x rows L2/L3-hot from the chunk loop) ----
    float4* __restrict__ OUT4 = reinterpret_cast<float4*>(out);
    #pragma unroll
    for (int it = 0; it < 4; ++it) {
        const int i  = tid + (it << 8);   // 0..1023 -> (b, e4)
        const int b  = i >> 7;
        const int e4 = i & 127;
        float4 sc = make_float4(0.f, 0.f, 0.f, 0.f);
        #pragma unroll
        for (int w = 0; w < WIN_; ++w) {
            const int r = s - WW + w;
            if (r >= 0 && r < S_) {
                const float g   = gates[b * WIN_ + w];
                const float4 xv = X4[((size_t)b * S_ + r) * E4C + e4];
                sc.x = fmaf(g, xv.x, sc.x);
                sc.y = fmaf(g, xv.y, sc.y);
                sc.z = fmaf(g, xv.z, sc.z);
                sc.w = fmaf(g, xv.w, sc.w);
            }
        }
        float4 o;
        o.x = tanh_fast(sc.x);
        o.y = tanh_fast(sc.y);
        o.z = tanh_fast(sc.z);
        o.w = tanh_fast(sc.w);
        OUT4[((size_t)b * S_ + s) * E4C + e4] = o;
    }
}

extern "C" void kernel_launch(void* const* d_in, const int* in_sizes, int n_in,
                              void* d_out, int out_size, void* d_ws, size_t ws_size,
                              hipStream_t stream)
{
    const float* x    = (const float*)d_in[0];
    const float* W    = (const float*)d_in[1];
    const float* bias = (const float*)d_in[2];
    float* out        = (float*)d_out;

    win_attn_fused<<<dim3(S_), dim3(256), 0, stream>>>(x, W, bias, out);
}

// Round 12
// 146.569 us; speedup vs baseline: 1.0718x; 1.0718x over previous
//
#include <hip/hip_runtime.h>
#include <math.h>

// Problem constants (B, S, E, WIN) = (8, 2048, 512, 11)
#define B_    8
#define S_    2048
#define E_    512
#define WIN_  11
#define WW    5              // WIN/2
#define F4C   1408           // float4 per W row (5632/4)
#define E4C   128            // float4 per x row (512/4)
#define PSTR  (B_ * WIN_)    // 88 gate logits per s
#define HC_W  704            // W float4 per half-chunk (11 rows x 64)
#define HC_X  512            // x float4 per half-chunk (8 batches x 64)

// ---- DPP wave-sum: 6 VALU ops, zero DS-pipe traffic. Full sum -> lane 63.
template <int CTRL, int RMASK>
__device__ __forceinline__ float dpp_add(float v) {
    int sh = __builtin_amdgcn_update_dpp(0, __float_as_int(v),
                                         CTRL, RMASK, 0xF, true);
    return v + __int_as_float(sh);
}
__device__ __forceinline__ float wave_sum63(float v) {
    v = dpp_add<0x111, 0xF>(v);   // row_shr:1
    v = dpp_add<0x112, 0xF>(v);   // row_shr:2
    v = dpp_add<0x114, 0xF>(v);   // row_shr:4
    v = dpp_add<0x118, 0xF>(v);   // row_shr:8
    v = dpp_add<0x142, 0xA>(v);   // row_bcast:15
    v = dpp_add<0x143, 0xC>(v);   // row_bcast:31 -> lane 63 = full sum
    return v;
}

__device__ __forceinline__ float tanh_fast(float v) {
    const float e = __expf(v + v);
    return 1.f - 2.f / (e + 1.f);
}

// ---------------------------------------------------------------------------
// R12 = R10 (x-dedup, gl_lds, 4 blocks/CU) + counted-vmcnt double buffer at
// HALF-CHUNK granularity (the R11 pipeline schedule, but without the
// occupancy loss that killed it: 2x19.5KB = 38.9 KB LDS keeps 4 blocks/CU).
// Chunk c = (wp = c>>1, h = c&1): W[s, :, wp*512+h*256 : +256] (11x64 f4)
// + x[:, s-5+wp, h*256:+256] (8x64 f4). Per iter:
//   STAGE(buf^1, c+1)            -> next chunk's 5 (4) gl_lds issued
//   s_waitcnt vmcnt(5|4)         -> waits ONLY for cur's loads; next's fly
//   s_barrier                    -> cross-wave RAW on cur complete
//   compute(buf)                 -> 11 ds_read_b128 + 96 FMA per thread
//   s_barrier                    -> WAR before buf is overwritten next iter
// Wave g owns w-rows 3g..3g+2 for all 8 batches; lane covers the 64-f4 slice.
// ---------------------------------------------------------------------------
__global__ __launch_bounds__(256)
void win_attn_fused(const float* __restrict__ x,
                    const float* __restrict__ W,
                    const float* __restrict__ bias,
                    float* __restrict__ out)
{
    const int bid  = blockIdx.x;
    const int s    = (bid & 7) * (S_ / 8) + (bid >> 3);   // bijective XCD swizzle
    const int tid  = threadIdx.x;
    const int wid  = tid >> 6;      // wave 0..3
    const int lane = tid & 63;

    const float4* __restrict__ X4 = reinterpret_cast<const float4*>(x);
    const float4* __restrict__ Ws = reinterpret_cast<const float4*>(W)
                                    + (size_t)s * (WIN_ * F4C);

    __shared__ float4 Wb[2][HC_W];   // 2 x 11.0 KB
    __shared__ float4 xb[2][HC_X];   // 2 x 8.0 KB
    __shared__ float gates[PSTR];

    const int w0   = wid * 3;                  // first w-row of this wave
    const int wcnt = (wid == 3) ? 2 : 3;       // wave 3 owns rows 9,10

    // stage half-chunk c into buffer `buf`; waves 0-2 issue 5 gl_lds, wave 3: 4
    auto STAGE = [&](int buf, int c) {
        const int wp  = c >> 1;
        const int h   = c & 1;
        const int row = s - WW + wp;
        // W: 704 f4; m = w*64 + e_local
        #pragma unroll
        for (int j = 0; j < 3; ++j) {
            const int m = j * 256 + tid;
            if (j < 2 || tid < 192) {          // wave-uniform (m < 704)
                const int w  = m >> 6;
                const int el = m & 63;
                const float4* src = Ws + (size_t)w * F4C + wp * E4C + h * 64 + el;
                __builtin_amdgcn_global_load_lds(
                    (const __attribute__((address_space(1))) void*)src,
                    (__attribute__((address_space(3))) void*)&Wb[buf][m],
                    16, 0, 0);
            }
        }
        // x: 512 f4; n = b*64 + e_local
        #pragma unroll
        for (int j = 0; j < 2; ++j) {
            const int n  = j * 256 + tid;
            const int b  = n >> 6;
            const int el = n & 63;
            const float4* src = X4 + ((size_t)b * S_ + row) * E4C + h * 64 + el;
            __builtin_amdgcn_global_load_lds(
                (const __attribute__((address_space(1))) void*)src,
                (__attribute__((address_space(3))) void*)&xb[buf][n],
                16, 0, 0);
        }
    };

    float acc[B_][3];
    #pragma unroll
    for (int b = 0; b < B_; ++b)
        #pragma unroll
        for (int j = 0; j < 3; ++j) acc[b][j] = 0.f;

    const int wpLo = (s >= WW) ? 0 : (WW - s);
    const int wpHi = (WIN_ < S_ + WW - s) ? WIN_ : (S_ + WW - s);
    const int cLo  = 2 * wpLo, cHi = 2 * wpHi;

    STAGE(0, cLo);
    int cur = 0;

    #pragma unroll 1
    for (int c = cLo; c < cHi; ++c) {
        const bool more = (c + 1 < cHi);
        if (more) STAGE(cur ^ 1, c + 1);   // next half-chunk flies over compute

        if (more) {
            if (wid < 3) asm volatile("s_waitcnt vmcnt(5)" ::: "memory");
            else         asm volatile("s_waitcnt vmcnt(4)" ::: "memory");
        } else {
            asm volatile("s_waitcnt vmcnt(0)" ::: "memory");
        }
        __builtin_amdgcn_s_barrier();        // all waves' cur loads complete
        __builtin_amdgcn_sched_barrier(0);   // no ds_read hoist above the wait

        // ---- compute half-chunk c from buf[cur] ----
        float4 wv[3];
        #pragma unroll
        for (int j = 0; j < 3; ++j)
            if (j < wcnt) wv[j] = Wb[cur][(w0 + j) * 64 + lane];

        float4 xv[B_];
        #pragma unroll
        for (int b = 0; b < B_; ++b) xv[b] = xb[cur][b * 64 + lane];

        #pragma unroll
        for (int b = 0; b < B_; ++b)
            #pragma unroll
            for (int j = 0; j < 3; ++j)
                if (j < wcnt) {
                    float a = acc[b][j];
                    a = fmaf(xv[b].x, wv[j].x, a);
                    a = fmaf(xv[b].y, wv[j].y, a);
                    a = fmaf(xv[b].z, wv[j].z, a);
                    a = fmaf(xv[b].w, wv[j].w, a);
                    acc[b][j] = a;
                }

        __builtin_amdgcn_s_barrier();   // WAR: reads done before overwrite
        cur ^= 1;
    }

    // ---- DPP reduce (VALU only) -> gate logits -> sigmoid ----
    #pragma unroll
    for (int b = 0; b < B_; ++b)
        #pragma unroll
        for (int j = 0; j < 3; ++j)
            if (j < wcnt) acc[b][j] = wave_sum63(acc[b][j]);

    if (lane == 63) {
        #pragma unroll
        for (int b = 0; b < B_; ++b)
            #pragma unroll
            for (int j = 0; j < 3; ++j)
                if (j < wcnt) gates[b * WIN_ + w0 + j] = acc[b][j];
    }
    __syncthreads();

    if (tid < PSTR) {
        const int w = tid % WIN_;
        const float v = gates[tid] + bias[s * WIN_ + w];
        gates[tid] = 1.f / (1.f + __expf(-v));
    }
    __syncthreads();

    // ---- score + tanh (x rows L2/L3-hot from the chunk loop) ----
    float4* __restrict__ OUT4 = reinterpret_cast<float4*>(out);
    #pragma unroll
    for (int it = 0; it < 4; ++it) {
        const int i  = tid + (it << 8);   // 0..1023 -> (b, e4)
        const int b  = i >> 7;
        const int e4 = i & 127;
        float4 sc = make_float4(0.f, 0.f, 0.f, 0.f);
        #pragma unroll
        for (int w = 0; w < WIN_; ++w) {
            const int r = s - WW + w;
            if (r >= 0 && r < S_) {
                const float g   = gates[b * WIN_ + w];
                const float4 xv = X4[((size_t)b * S_ + r) * E4C + e4];
                sc.x = fmaf(g, xv.x, sc.x);
                sc.y = fmaf(g, xv.y, sc.y);
                sc.z = fmaf(g, xv.z, sc.z);
                sc.w = fmaf(g, xv.w, sc.w);
            }
        }
        float4 o;
        o.x = tanh_fast(sc.x);
        o.y = tanh_fast(sc.y);
        o.z = tanh_fast(sc.z);
        o.w = tanh_fast(sc.w);
        OUT4[((size_t)b * S_ + s) * E4C + e4] = o;
    }
}

extern "C" void kernel_launch(void* const* d_in, const int* in_sizes, int n_in,
                              void* d_out, int out_size, void* d_ws, size_t ws_size,
                              hipStream_t stream)
{
    const float* x    = (const float*)d_in[0];
    const float* W    = (const float*)d_in[1];
    const float* bias = (const float*)d_in[2];
    float* out        = (float*)d_out;

    win_attn_fused<<<dim3(S_), dim3(256), 0, stream>>>(x, W, bias, out);
}